// Round 1
// baseline (239.805 us; speedup 1.0000x reference)
//
#include <hip/hip_runtime.h>

// SeaThru-NeRF RGB renderer forward pass.
// Layout: one wave (64 lanes) per ray; lane t owns samples 4t..4t+3.
// All global loads/stores are coalesced float4 (16B/lane).

__device__ __forceinline__ float clip01(float x) {
    return fminf(fmaxf(x, 0.0f), 1.0f);
}

// Exclusive prefix sum across the 64-lane wave.
__device__ __forceinline__ float wave_exscan(float v, int lane) {
    float x = v;
#pragma unroll
    for (int off = 1; off < 64; off <<= 1) {
        float y = __shfl_up(x, off, 64);
        x += (lane >= off) ? y : 0.0f;
    }
    return x - v;  // inclusive -> exclusive
}

__device__ __forceinline__ float wave_sum(float v) {
#pragma unroll
    for (int off = 32; off; off >>= 1) v += __shfl_xor(v, off, 64);
    return v;
}

__global__ __launch_bounds__(256) void seathru_render(
    const float* __restrict__ g_orgb,   // [R,S,3] object_rgbs
    const float* __restrict__ g_mrgb,   // [R,S,3] medium_rgbs
    const float* __restrict__ g_dc,     // [R,S,3] direct_coeffs
    const float* __restrict__ g_bc,     // [R,S,3] backscatter_coeffs
    const float* __restrict__ g_den,    // [R,S,1] densities
    const float* __restrict__ g_del,    // [R,S,1] deltas
    float* __restrict__ out, int R)
{
    const int S = 256;
    const int ray  = blockIdx.x * 4 + (threadIdx.x >> 6);
    const int lane = threadIdx.x & 63;
    if (ray >= R) return;

    const size_t b3 = (size_t)ray * (S * 3);  // float offset into 3-channel arrays
    const size_t b1 = (size_t)ray * S;        // float offset into 1-channel arrays
    const size_t RS = (size_t)R * S;

    // ---- loads: 12 floats per lane per 3ch array (3x float4), 4 per 1ch ----
    float orv[12], mrv[12], dcv[12], bcv[12];
    {
        const float4* p = (const float4*)(g_orgb + b3) + lane * 3;
        *(float4*)&orv[0] = p[0]; *(float4*)&orv[4] = p[1]; *(float4*)&orv[8] = p[2];
    }
    {
        const float4* p = (const float4*)(g_mrgb + b3) + lane * 3;
        *(float4*)&mrv[0] = p[0]; *(float4*)&mrv[4] = p[1]; *(float4*)&mrv[8] = p[2];
    }
    {
        const float4* p = (const float4*)(g_dc + b3) + lane * 3;
        *(float4*)&dcv[0] = p[0]; *(float4*)&dcv[4] = p[1]; *(float4*)&dcv[8] = p[2];
    }
    {
        const float4* p = (const float4*)(g_bc + b3) + lane * 3;
        *(float4*)&bcv[0] = p[0]; *(float4*)&bcv[4] = p[1]; *(float4*)&bcv[8] = p[2];
    }
    float4 dl4 = *((const float4*)(g_del + b1) + lane);
    float4 dn4 = *((const float4*)(g_den + b1) + lane);
    float del[4] = {dl4.x, dl4.y, dl4.z, dl4.w};
    float den[4] = {dn4.x, dn4.y, dn4.z, dn4.w};

    // ---- object transmittance / alpha / weights (scalar channel) ----
    float dd[4], ex_dd[4];
    float run = 0.0f;
#pragma unroll
    for (int i = 0; i < 4; ++i) { dd[i] = del[i] * den[i]; ex_dd[i] = run; run += dd[i]; }
    const float off_dd = wave_exscan(run, lane);

    float T[4], alpha[4], w[4];
#pragma unroll
    for (int i = 0; i < 4; ++i) {
        T[i]     = __expf(-(off_dd + ex_dd[i]));   // exclusive cumsum -> exp
        alpha[i] = 1.0f - __expf(-dd[i]);
        w[i]     = T[i] * alpha[i];
    }

    // ---- per-sample outputs (coalesced float4 stores) ----
    float* outT = out + (size_t)12 * R;       // object_transmittance [R,S]
    float* outA = outT + RS;                  // object_alphas
    float* outW = outA + RS;                  // object_weights
    {
        float4 t4 = {T[0], T[1], T[2], T[3]};
        float4 a4 = {alpha[0], alpha[1], alpha[2], alpha[3]};
        float4 w4 = {w[0], w[1], w[2], w[3]};
        *((float4*)(outT + b1) + lane) = t4;
        *((float4*)(outA + b1) + lane) = a4;
        *((float4*)(outW + b1) + lane) = w4;
    }

    // ---- per-channel direct / backscatter scans + weighted sums ----
    float acc_dir[3], acc_bs[3], acc_rest[3];
    float acc_mask = w[0] + w[1] + w[2] + w[3];

#pragma unroll
    for (int c = 0; c < 3; ++c) {
        // direct attenuation channel c
        float dcd[4], exd[4], rund = 0.0f;
#pragma unroll
        for (int i = 0; i < 4; ++i) { dcd[i] = dcv[i * 3 + c] * del[i]; exd[i] = rund; rund += dcd[i]; }
        const float offd = wave_exscan(rund, lane);

        float ad = 0.0f, ar = 0.0f;
#pragma unroll
        for (int i = 0; i < 4; ++i) {
            const float da = __expf(-(offd + exd[i]));
            const float o  = orv[i * 3 + c];
            ad += T[i] * da * alpha[i] * o;
            ar += w[i] * o;
        }
        acc_dir[c] = ad;
        acc_rest[c] = ar;

        // backscatter channel c
        float bsd[4], exb[4], runb = 0.0f;
#pragma unroll
        for (int i = 0; i < 4; ++i) { bsd[i] = bcv[i * 3 + c] * del[i]; exb[i] = runb; runb += bsd[i]; }
        const float offb = wave_exscan(runb, lane);

        float ab = 0.0f;
#pragma unroll
        for (int i = 0; i < 4; ++i) {
            const float B  = __expf(-(offb + exb[i]));
            const float ma = 1.0f - __expf(-bsd[i]);
            ab += T[i] * B * ma * mrv[i * 3 + c];
        }
        acc_bs[c] = ab;
    }

    // ---- wave reductions (10 scalars) ----
#pragma unroll
    for (int c = 0; c < 3; ++c) {
        acc_dir[c]  = wave_sum(acc_dir[c]);
        acc_bs[c]   = wave_sum(acc_bs[c]);
        acc_rest[c] = wave_sum(acc_rest[c]);
    }
    acc_mask = wave_sum(acc_mask);

    // ---- per-ray outputs (lane 0) ----
    if (lane == 0) {
        float* rgb  = out;                                  // [R,3]
        float* rest = out + (size_t)3 * R;                  // [R,3]
        float* dir  = out + (size_t)6 * R;                  // [R,3]
        float* bs   = out + (size_t)9 * R;                  // [R,3]
        float* dc0  = out + (size_t)12 * R + 3 * RS;        // direct_coeffs[:,0,:]
        float* bc0  = dc0 + (size_t)3 * R;                  // backscatter_coeffs[:,0,:]
        float* mask = bc0 + (size_t)3 * R;                  // [R,1]
#pragma unroll
        for (int c = 0; c < 3; ++c) {
            const float d = acc_dir[c], b = acc_bs[c];
            rgb[ray * 3 + c]  = clip01(d + b);
            rest[ray * 3 + c] = clip01(acc_rest[c]);
            dir[ray * 3 + c]  = clip01(d);
            bs[ray * 3 + c]   = clip01(b);
            dc0[ray * 3 + c]  = dcv[c];   // lane 0, sample 0, channel c
            bc0[ray * 3 + c]  = bcv[c];
        }
        mask[ray] = clip01(acc_mask);
    }
}

extern "C" void kernel_launch(void* const* d_in, const int* in_sizes, int n_in,
                              void* d_out, int out_size, void* d_ws, size_t ws_size,
                              hipStream_t stream) {
    const float* orgb = (const float*)d_in[0];
    const float* mrgb = (const float*)d_in[1];
    const float* dc   = (const float*)d_in[2];
    const float* bc   = (const float*)d_in[3];
    const float* den  = (const float*)d_in[4];
    const float* del  = (const float*)d_in[5];

    const int S = 256;
    const int R = in_sizes[0] / (S * 3);

    dim3 block(256);                 // 4 waves = 4 rays per block
    dim3 grid((R + 3) / 4);
    seathru_render<<<grid, block, 0, stream>>>(orgb, mrgb, dc, bc, den, del,
                                               (float*)d_out, R);
}